// Round 9
// baseline (382.791 us; speedup 1.0000x reference)
//
#include <hip/hip_runtime.h>
#include <hip/hip_bf16.h>
#include <stdint.h>

#define D_ 32
#define H_ 128
#define W_ 128
#define NCIN 16
#define NCOUT 32
#define NVOX 200000
#define NB 4
#define PD (D_ + 4)
#define PH (H_ + 4)
#define PW (W_ + 4)

// spatial tiles: 8x8x8 cells, staged with +2 halo into LDS (12^3 cells x 32B)
#define NTZ 4
#define NTY 16
#define NTX 16
#define NTILES (NB * NTZ * NTY * NTX)   // 4096
#define NKEY (NTILES * 27)              // 110592
#define GCAP 64                         // max 16-voxel groups per tile (worst case 58)
#define HALO_BYTES 55296                // 12*12*12*32
#define NCHUNK 75                       // 25 (dz,dy) rows x 3 x-chunks (dx=5 padded with B=0)

typedef __attribute__((ext_vector_type(8))) short bf16x8;
typedef __attribute__((ext_vector_type(4))) float f32x4;

__device__ __forceinline__ int vox_off(int b, int z, int y, int x) {
    return ((((b * PD + (z + 2)) * PH + (y + 2)) * PW + (x + 2))) * NCIN;
}
__device__ __forceinline__ int cls_of(int z, int y, int x) {
    int cz = (z == 0) ? 0 : ((z == D_ - 1) ? 2 : 1);
    int cy = (y == 0) ? 0 : ((y == H_ - 1) ? 2 : 1);
    int cx = (x == 0) ? 0 : ((x == W_ - 1) ? 2 : 1);
    return (cz * 3 + cy) * 3 + cx;
}
__device__ __forceinline__ int tile_of(int b, int z, int y, int x) {
    return ((b * NTZ + (z >> 3)) * NTY + (y >> 3)) * NTX + (x >> 3);
}

// ---------------------------------------------------------------------------
// Stage A: pairwise products P[k1][k2][ci][cf] = sum_cm W1[k1,ci,cm]*W2[k2,cm,cf].
// ---------------------------------------------------------------------------
__global__ void wc_p_kernel(const float* __restrict__ W1, const float* __restrict__ W2,
                            float* __restrict__ P) {
    int k12 = blockIdx.x;            // k1*27 + k2
    int k1 = k12 / 27, k2 = k12 % 27;
    __shared__ float w1s[512], w2s[512];
    int t = threadIdx.x;             // 256
    w1s[t] = W1[k1 * 512 + t];       w1s[t + 256] = W1[k1 * 512 + 256 + t];
    w2s[t] = W2[k2 * 512 + t];       w2s[t + 256] = W2[k2 * 512 + 256 + t];
    __syncthreads();
    int ci = t >> 4, cf = t & 15;
    float acc = 0.f;
    #pragma unroll
    for (int cm = 0; cm < 32; ++cm)
        acc = fmaf(w1s[ci * 32 + cm], w2s[cm * 16 + cf], acc);
    P[k12 * 256 + t] = acc;
}

// ---------------------------------------------------------------------------
// Stage B: combined weights in MFMA B-fragment layout over 75 chunks:
// WcB[cls][rj=(dz*5+dy)*3+j][lane][jj]; k=(lane>>4)*8+jj; cell=k>>4; ci=k&15;
// cf=lane&15; dx = 2*j+cell (dx>=5 -> zero); delta = (dz*5+dy)*5 + dx.
// ---------------------------------------------------------------------------
__global__ void wc_pack2_kernel(const float* __restrict__ P, __hip_bfloat16* __restrict__ WcB) {
    int blk = blockIdx.x;            // cls*75 + rj
    int cls = blk / NCHUNK, rj = blk % NCHUNK;
    int r = rj / 3, j = rj % 3;
    int dz = r / 5, dy = r % 5;
    int t = threadIdx.x;             // 512
    int l = t >> 3, jj = t & 7;
    int k = (l >> 4) * 8 + jj;
    int ld = k >> 4, ci = k & 15, cf = l & 15;
    int dx = 2 * j + ld;
    float acc = 0.f;
    if (dx < 5) {
        int sz = dz, sy = dy, sx = dx;
        int cz = cls / 9, cy = (cls / 3) % 3, cx = cls % 3;
        for (int k1z = 0; k1z < 3; ++k1z) {
            int k2z = sz - k1z;
            if (k2z < 0 || k2z > 2) continue;
            if ((cz == 0 && k2z == 0) || (cz == 2 && k2z == 2)) continue;
            for (int k1y = 0; k1y < 3; ++k1y) {
                int k2y = sy - k1y;
                if (k2y < 0 || k2y > 2) continue;
                if ((cy == 0 && k2y == 0) || (cy == 2 && k2y == 2)) continue;
                for (int k1x = 0; k1x < 3; ++k1x) {
                    int k2x = sx - k1x;
                    if (k2x < 0 || k2x > 2) continue;
                    if ((cx == 0 && k2x == 0) || (cx == 2 && k2x == 2)) continue;
                    int k1 = (k1z * 3 + k1y) * 3 + k1x;
                    int k2 = (k2z * 3 + k2y) * 3 + k2x;
                    acc += P[(k1 * 27 + k2) * 256 + ci * 16 + cf];
                }
            }
        }
    }
    WcB[(size_t)blk * 512 + t] = __float2bfloat16(acc);
}

// ---------------------------------------------------------------------------
// Scatter features into padded bf16 dense grid + per-(tile,cls) histogram.
// ---------------------------------------------------------------------------
__global__ void scatter_count_kernel(const float* __restrict__ feats,
                                     const int* __restrict__ coors,
                                     __hip_bfloat16* __restrict__ dense,
                                     unsigned int* __restrict__ cnt) {
    int t = blockIdx.x * blockDim.x + threadIdx.x;
    if (t >= NVOX * NCIN) return;
    int v = t >> 4, c = t & 15;
    const int4* c4 = (const int4*)coors;
    int4 q = c4[v];
    dense[vox_off(q.x, q.y, q.z, q.w) + c] = __float2bfloat16(feats[t]);
    if (c == 0) {
        int key = tile_of(q.x, q.y, q.z, q.w) * 27 + cls_of(q.y, q.z, q.w);
        atomicAdd(&cnt[key], 1u);
    }
}

// ---------------------------------------------------------------------------
// Single-block prep: per-tile voxel prefix (tile-major list layout), per-key
// list offsets, and per-tile 16-voxel group descriptors. Replaces 3 kernels.
// ---------------------------------------------------------------------------
__global__ void prep_kernel(const unsigned int* __restrict__ cnt,
                            unsigned int* __restrict__ cur,
                            uint2* __restrict__ gdesc,
                            unsigned int* __restrict__ ngroups) {
    __shared__ unsigned sv[1024];
    int t = threadIdx.x;
    unsigned tot = 0;
    for (int i = 0; i < 4; ++i) {
        int tile = t * 4 + i;
        for (int c = 0; c < 27; ++c) tot += cnt[tile * 27 + c];
    }
    sv[t] = tot;
    __syncthreads();
    for (int o = 1; o < 1024; o <<= 1) {
        unsigned a = (t >= o) ? sv[t - o] : 0u;
        __syncthreads();
        sv[t] += a;
        __syncthreads();
    }
    unsigned vo = sv[t] - tot;      // exclusive voxel base for tile 4t
    for (int i = 0; i < 4; ++i) {
        int tile = t * 4 + i;
        unsigned g = 0;
        for (int c = 0; c < 27; ++c) {
            int key = tile * 27 + c;
            unsigned cc = cnt[key];
            cur[key] = vo;
            for (unsigned o2 = 0; o2 < cc; o2 += 16) {
                unsigned r = cc - o2; if (r > 16) r = 16;
                gdesc[tile * GCAP + g] = make_uint2(vo + o2, (unsigned)c | (r << 16));
                ++g;
            }
            vo += cc;
        }
        ngroups[tile] = g;
    }
}

__global__ void bucket_kernel(const int* __restrict__ coors,
                              unsigned int* __restrict__ cur,
                              unsigned int* __restrict__ list) {
    int v = blockIdx.x * blockDim.x + threadIdx.x;
    if (v >= NVOX) return;
    const int4* c4 = (const int4*)coors;
    int4 q = c4[v];
    int key = tile_of(q.x, q.y, q.z, q.w) * 27 + cls_of(q.y, q.z, q.w);
    unsigned pos = atomicAdd(&cur[key], 1u);
    list[pos] = (unsigned)v;
}

// ---------------------------------------------------------------------------
// Main: one block per tile. Stage tile+halo (54KB) into LDS via
// global_load_lds, then per 16-voxel group run 75 MFMA chunks with A from LDS
// (all offsets compile-time) and B streamed from L2. dx=5 pad has B=0; LDS
// tail is zeroed so padded A-reads stay finite.
// ---------------------------------------------------------------------------
__global__ void __launch_bounds__(256, 2) main_kernel(
        const int* __restrict__ coors, const __hip_bfloat16* __restrict__ dense,
        const __hip_bfloat16* __restrict__ WcB, const uint2* __restrict__ gdesc,
        const unsigned int* __restrict__ ngroups, const unsigned int* __restrict__ list,
        float* __restrict__ out) {
    __shared__ uint4 halo4[(HALO_BYTES + 64) / 16];   // 55360 B
    unsigned char* halo = (unsigned char*)halo4;
    int t = threadIdx.x;
    int w = t >> 6, lane = t & 63;
    int col = lane & 15, halfsel = (lane >> 4) & 1, dsel = lane >> 5;

    int bid = blockIdx.x;
    int tid = (bid & 7) * (NTILES / 8) + (bid >> 3);   // XCD swizzle; 4096%8==0
    int ng = (int)ngroups[tid];
    if (ng == 0) return;
    int tx = tid & 15, r1 = tid >> 4;
    int ty = r1 & 15, r2 = r1 >> 4;
    int tz = r2 & 3, b = r2 >> 2;
    int pz = tz * 8, py = ty * 8, px = tx * 8;

    // ---- stage: 6912 half-cells (16B each), 27 iters x 4 waves x 64 lanes ----
    for (int i = 0; i < 27; ++i) {
        int hw = i * 4 + w;                 // wave-chunk id (uniform per wave)
        int hc = hw * 64 + lane;            // half-cell id
        int cell = hc >> 1, half = hc & 1;
        int cz = cell / 144;
        int rc = cell - cz * 144;
        int cy = rc / 12;
        int cx = rc - cy * 12;
        const __hip_bfloat16* gp = dense +
            (((b * PD + pz + cz) * PH + (py + cy)) * PW + (px + cx)) * NCIN + half * 8;
        __builtin_amdgcn_global_load_lds(
            (const __attribute__((address_space(1))) void*)gp,
            (__attribute__((address_space(3))) void*)(halo + hw * 1024), 16, 0, 0);
    }
    if (t < 4) halo4[3456 + t] = make_uint4(0u, 0u, 0u, 0u);  // zero 64B pad tail
    __syncthreads();

    const int4* c4 = (const int4*)coors;
    for (int g = w; g < ng; g += 4) {
        uint2 dsc = gdesc[tid * GCAP + g];
        unsigned off = dsc.x;
        int cls = (int)(dsc.y & 0xffffu);
        int cnt = (int)(dsc.y >> 16);
        int rr = min(col, cnt - 1);
        unsigned v = list[off + rr];
        int4 q = c4[v];
        int vz = q.y - pz, vy = q.z - py, vx = q.w - px;
        int abase = ((vz * 12 + vy) * 12 + vx) * 32 + dsel * 32 + halfsel * 16;
        const bf16x8* bq = (const bf16x8*)WcB + (size_t)cls * (NCHUNK * 64) + lane;

        f32x4 acc = {0.f, 0.f, 0.f, 0.f};
        #pragma unroll 1
        for (int dz = 0; dz < 5; ++dz) {
            #pragma unroll
            for (int dy = 0; dy < 5; ++dy) {
                int ab = abase + (dz * 144 + dy * 12) * 32;
                bf16x8 a0 = *(const bf16x8*)(halo + ab);
                bf16x8 a1 = *(const bf16x8*)(halo + ab + 64);
                bf16x8 a2 = *(const bf16x8*)(halo + ab + 128);
                int ci0 = (dz * 5 + dy) * 3;
                bf16x8 b0 = bq[ci0 * 64];
                bf16x8 b1 = bq[ci0 * 64 + 64];
                bf16x8 b2 = bq[ci0 * 64 + 128];
                acc = __builtin_amdgcn_mfma_f32_16x16x32_bf16(a0, b0, acc, 0, 0, 0);
                acc = __builtin_amdgcn_mfma_f32_16x16x32_bf16(a1, b1, acc, 0, 0, 0);
                acc = __builtin_amdgcn_mfma_f32_16x16x32_bf16(a2, b2, acc, 0, 0, 0);
            }
        }
        int rowq = (lane >> 4) * 4;
        #pragma unroll
        for (int reg = 0; reg < 4; ++reg) {
            int orow = rowq + reg;
            if (orow < cnt) {
                unsigned vo = list[off + orow];
                out[(size_t)vo * 16 + col] = acc[reg];
            }
        }
    }
}

extern "C" void kernel_launch(void* const* d_in, const int* in_sizes, int n_in,
                              void* d_out, int out_size, void* d_ws, size_t ws_size,
                              hipStream_t stream) {
    const float* features = (const float*)d_in[0];
    const int*   coors    = (const int*)d_in[1];
    const float* W1       = (const float*)d_in[2];
    const float* W2       = (const float*)d_in[3];
    float* out = (float*)d_out;

    const size_t dense_elems = (size_t)NB * PD * PH * PW * NCIN;
    const size_t dense_bytes = dense_elems * sizeof(__hip_bfloat16);     // 80.3 MB
    char* p = (char*)d_ws;
    __hip_bfloat16* dense = (__hip_bfloat16*)p;
    p += ((dense_bytes + 255) / 256) * 256;
    __hip_bfloat16* WcB = (__hip_bfloat16*)p;                            // 27*75*512*2 = 2.07MB
    p += (((size_t)27 * NCHUNK * 512 * 2 + 255) / 256) * 256;
    unsigned int* cnt = (unsigned int*)p;                                // NKEY*4 = 442KB
    p += (((size_t)NKEY * 4 + 255) / 256) * 256;
    unsigned int* cur = (unsigned int*)p;                                // 442KB
    p += (((size_t)NKEY * 4 + 255) / 256) * 256;
    unsigned int* ngroups = (unsigned int*)p; p += NTILES * 4;           // 16KB
    uint2* gdesc = (uint2*)p;                                            // 2MB
    p += (size_t)NTILES * GCAP * 8;
    unsigned int* list = (unsigned int*)p;                               // 800KB
    float* P = (float*)list;        // wc scratch aliases list (746KB <= 800KB; used before bucket)

    hipMemsetAsync(dense, 0, dense_bytes, stream);
    hipMemsetAsync(cnt, 0, (size_t)NKEY * 4, stream);

    wc_p_kernel<<<729, 256, 0, stream>>>(W1, W2, P);
    wc_pack2_kernel<<<27 * NCHUNK, 512, 0, stream>>>(P, WcB);
    scatter_count_kernel<<<(NVOX * NCIN + 255) / 256, 256, 0, stream>>>(features, coors, dense, cnt);
    prep_kernel<<<1, 1024, 0, stream>>>(cnt, cur, gdesc, ngroups);
    bucket_kernel<<<(NVOX + 255) / 256, 256, 0, stream>>>(coors, cur, list);
    main_kernel<<<NTILES, 256, 0, stream>>>(coors, dense, WcB, gdesc, ngroups, list, out);
}

// Round 14
// 238.902 us; speedup vs baseline: 1.6023x; 1.6023x over previous
//
#include <hip/hip_runtime.h>
#include <hip/hip_bf16.h>
#include <stdint.h>

#define D_ 32
#define H_ 128
#define W_ 128
#define NCIN 16
#define NCOUT 32
#define NVOX 200000
#define NB 4
#define PD (D_ + 4)
#define PH (H_ + 4)
#define PW (W_ + 4)

// spatial tiles: 8x8x8 cells, staged with +2 halo into LDS (12^3 cells x 32B)
#define NTZ 4
#define NTY 16
#define NTX 16
#define NTILES (NB * NTZ * NTY * NTX)   // 4096
#define NKEY (NTILES * 27)              // 110592
#define GCAP 64                         // max 16-voxel groups per tile (worst case 58)
#define HALO_BYTES 55296                // 12*12*12*32
#define NCHUNK 75                       // 25 (dz,dy) rows x 3 x-chunks (dx=5 padded with B=0)

typedef __attribute__((ext_vector_type(8))) short bf16x8;
typedef __attribute__((ext_vector_type(4))) float f32x4;

__device__ __forceinline__ int vox_off(int b, int z, int y, int x) {
    return ((((b * PD + (z + 2)) * PH + (y + 2)) * PW + (x + 2))) * NCIN;
}
__device__ __forceinline__ int cls_of(int z, int y, int x) {
    int cz = (z == 0) ? 0 : ((z == D_ - 1) ? 2 : 1);
    int cy = (y == 0) ? 0 : ((y == H_ - 1) ? 2 : 1);
    int cx = (x == 0) ? 0 : ((x == W_ - 1) ? 2 : 1);
    return (cz * 3 + cy) * 3 + cx;
}
__device__ __forceinline__ int tile_of(int b, int z, int y, int x) {
    return ((b * NTZ + (z >> 3)) * NTY + (y >> 3)) * NTX + (x >> 3);
}

// ---------------------------------------------------------------------------
// Stage A: pairwise products P[k1][k2][ci][cf] = sum_cm W1[k1,ci,cm]*W2[k2,cm,cf].
// ---------------------------------------------------------------------------
__global__ void wc_p_kernel(const float* __restrict__ W1, const float* __restrict__ W2,
                            float* __restrict__ P) {
    int k12 = blockIdx.x;            // k1*27 + k2
    int k1 = k12 / 27, k2 = k12 % 27;
    __shared__ float w1s[512], w2s[512];
    int t = threadIdx.x;             // 256
    w1s[t] = W1[k1 * 512 + t];       w1s[t + 256] = W1[k1 * 512 + 256 + t];
    w2s[t] = W2[k2 * 512 + t];       w2s[t + 256] = W2[k2 * 512 + 256 + t];
    __syncthreads();
    int ci = t >> 4, cf = t & 15;
    float acc = 0.f;
    #pragma unroll
    for (int cm = 0; cm < 32; ++cm)
        acc = fmaf(w1s[ci * 32 + cm], w2s[cm * 16 + cf], acc);
    P[k12 * 256 + t] = acc;
}

// ---------------------------------------------------------------------------
// Stage B: combined weights in MFMA B-fragment layout over 75 chunks:
// WcB[cls][rj=(dz*5+dy)*3+j][lane][jj]; k=(lane>>4)*8+jj; cell=k>>4; ci=k&15;
// cf=lane&15; dx = 2*j+cell (dx>=5 -> zero); delta = (dz*5+dy)*5 + dx.
// ---------------------------------------------------------------------------
__global__ void wc_pack2_kernel(const float* __restrict__ P, __hip_bfloat16* __restrict__ WcB) {
    int blk = blockIdx.x;            // cls*75 + rj
    int cls = blk / NCHUNK, rj = blk % NCHUNK;
    int r = rj / 3, j = rj % 3;
    int dz = r / 5, dy = r % 5;
    int t = threadIdx.x;             // 512
    int l = t >> 3, jj = t & 7;
    int k = (l >> 4) * 8 + jj;
    int ld = k >> 4, ci = k & 15, cf = l & 15;
    int dx = 2 * j + ld;
    float acc = 0.f;
    if (dx < 5) {
        int sz = dz, sy = dy, sx = dx;
        int cz = cls / 9, cy = (cls / 3) % 3, cx = cls % 3;
        for (int k1z = 0; k1z < 3; ++k1z) {
            int k2z = sz - k1z;
            if (k2z < 0 || k2z > 2) continue;
            if ((cz == 0 && k2z == 0) || (cz == 2 && k2z == 2)) continue;
            for (int k1y = 0; k1y < 3; ++k1y) {
                int k2y = sy - k1y;
                if (k2y < 0 || k2y > 2) continue;
                if ((cy == 0 && k2y == 0) || (cy == 2 && k2y == 2)) continue;
                for (int k1x = 0; k1x < 3; ++k1x) {
                    int k2x = sx - k1x;
                    if (k2x < 0 || k2x > 2) continue;
                    if ((cx == 0 && k2x == 0) || (cx == 2 && k2x == 2)) continue;
                    int k1 = (k1z * 3 + k1y) * 3 + k1x;
                    int k2 = (k2z * 3 + k2y) * 3 + k2x;
                    acc += P[(k1 * 27 + k2) * 256 + ci * 16 + cf];
                }
            }
        }
    }
    WcB[(size_t)blk * 512 + t] = __float2bfloat16(acc);
}

// ---------------------------------------------------------------------------
// Scatter features into padded bf16 dense grid + per-(tile,cls) histogram.
// ---------------------------------------------------------------------------
__global__ void scatter_count_kernel(const float* __restrict__ feats,
                                     const int* __restrict__ coors,
                                     __hip_bfloat16* __restrict__ dense,
                                     unsigned int* __restrict__ cnt) {
    int t = blockIdx.x * blockDim.x + threadIdx.x;
    if (t >= NVOX * NCIN) return;
    int v = t >> 4, c = t & 15;
    const int4* c4 = (const int4*)coors;
    int4 q = c4[v];
    dense[vox_off(q.x, q.y, q.z, q.w) + c] = __float2bfloat16(feats[t]);
    if (c == 0) {
        int key = tile_of(q.x, q.y, q.z, q.w) * 27 + cls_of(q.y, q.z, q.w);
        atomicAdd(&cnt[key], 1u);
    }
}

// ---------------------------------------------------------------------------
// Parallel prep chain (round-9's single-block prep was 163us at 0.15% occ):
// 1) per-tile voxel totals; 2) 1-block scan over 4096 tiles; 3) per-tile emit.
// ---------------------------------------------------------------------------
__global__ void tile_cnt_kernel(const unsigned int* __restrict__ cnt,
                                unsigned int* __restrict__ vcnt) {
    int tile = blockIdx.x * blockDim.x + threadIdx.x;
    if (tile >= NTILES) return;
    unsigned vv = 0;
    for (int c = 0; c < 27; ++c) vv += cnt[tile * 27 + c];
    vcnt[tile] = vv;
}

__global__ void scan_kernel(const unsigned int* __restrict__ vcnt,
                            unsigned int* __restrict__ vbase) {
    __shared__ unsigned sv[1024];
    int t = threadIdx.x;
    unsigned c0 = vcnt[4 * t], c1 = vcnt[4 * t + 1], c2 = vcnt[4 * t + 2], c3 = vcnt[4 * t + 3];
    unsigned tot = c0 + c1 + c2 + c3;
    sv[t] = tot;
    __syncthreads();
    for (int o = 1; o < 1024; o <<= 1) {
        unsigned a = (t >= o) ? sv[t - o] : 0u;
        __syncthreads();
        sv[t] += a;
        __syncthreads();
    }
    unsigned vo = sv[t] - tot;
    vbase[4 * t] = vo;
    vbase[4 * t + 1] = vo + c0;
    vbase[4 * t + 2] = vo + c0 + c1;
    vbase[4 * t + 3] = vo + c0 + c1 + c2;
}

__global__ void emit_kernel(const unsigned int* __restrict__ cnt,
                            const unsigned int* __restrict__ vbase,
                            unsigned int* __restrict__ cur,
                            uint2* __restrict__ gdesc,
                            unsigned int* __restrict__ ngroups) {
    int tile = blockIdx.x * blockDim.x + threadIdx.x;
    if (tile >= NTILES) return;
    unsigned vo = vbase[tile];
    unsigned g = 0;
    for (int c = 0; c < 27; ++c) {
        int key = tile * 27 + c;
        unsigned cc = cnt[key];
        cur[key] = vo;
        for (unsigned o2 = 0; o2 < cc; o2 += 16) {
            unsigned r = cc - o2; if (r > 16) r = 16;
            gdesc[tile * GCAP + g] = make_uint2(vo + o2, (unsigned)c | (r << 16));
            ++g;
        }
        vo += cc;
    }
    ngroups[tile] = g;
}

__global__ void bucket_kernel(const int* __restrict__ coors,
                              unsigned int* __restrict__ cur,
                              unsigned int* __restrict__ list) {
    int v = blockIdx.x * blockDim.x + threadIdx.x;
    if (v >= NVOX) return;
    const int4* c4 = (const int4*)coors;
    int4 q = c4[v];
    int key = tile_of(q.x, q.y, q.z, q.w) * 27 + cls_of(q.y, q.z, q.w);
    unsigned pos = atomicAdd(&cur[key], 1u);
    list[pos] = (unsigned)v;
}

// ---------------------------------------------------------------------------
// Main: one block per tile. Stage tile+halo (54KB) into LDS via
// global_load_lds, then per 16-voxel group run 75 MFMA chunks with A from LDS
// (all offsets compile-time) and B streamed from L2. dx=5 pad has B=0; LDS
// tail is zeroed so padded A-reads stay finite. (Unchanged from round 9.)
// ---------------------------------------------------------------------------
__global__ void __launch_bounds__(256, 2) main_kernel(
        const int* __restrict__ coors, const __hip_bfloat16* __restrict__ dense,
        const __hip_bfloat16* __restrict__ WcB, const uint2* __restrict__ gdesc,
        const unsigned int* __restrict__ ngroups, const unsigned int* __restrict__ list,
        float* __restrict__ out) {
    __shared__ uint4 halo4[(HALO_BYTES + 64) / 16];   // 55360 B
    unsigned char* halo = (unsigned char*)halo4;
    int t = threadIdx.x;
    int w = t >> 6, lane = t & 63;
    int col = lane & 15, halfsel = (lane >> 4) & 1, dsel = lane >> 5;

    int bid = blockIdx.x;
    int tid = (bid & 7) * (NTILES / 8) + (bid >> 3);   // XCD swizzle; 4096%8==0
    int ng = (int)ngroups[tid];
    if (ng == 0) return;
    int tx = tid & 15, r1 = tid >> 4;
    int ty = r1 & 15, r2 = r1 >> 4;
    int tz = r2 & 3, b = r2 >> 2;
    int pz = tz * 8, py = ty * 8, px = tx * 8;

    // ---- stage: 6912 half-cells (16B each), 27 iters x 4 waves x 64 lanes ----
    for (int i = 0; i < 27; ++i) {
        int hw = i * 4 + w;                 // wave-chunk id (uniform per wave)
        int hc = hw * 64 + lane;            // half-cell id
        int cell = hc >> 1, half = hc & 1;
        int cz = cell / 144;
        int rc = cell - cz * 144;
        int cy = rc / 12;
        int cx = rc - cy * 12;
        const __hip_bfloat16* gp = dense +
            (((b * PD + pz + cz) * PH + (py + cy)) * PW + (px + cx)) * NCIN + half * 8;
        __builtin_amdgcn_global_load_lds(
            (const __attribute__((address_space(1))) void*)gp,
            (__attribute__((address_space(3))) void*)(halo + hw * 1024), 16, 0, 0);
    }
    if (t < 4) halo4[3456 + t] = make_uint4(0u, 0u, 0u, 0u);  // zero 64B pad tail
    __syncthreads();

    const int4* c4 = (const int4*)coors;
    for (int g = w; g < ng; g += 4) {
        uint2 dsc = gdesc[tid * GCAP + g];
        unsigned off = dsc.x;
        int cls = (int)(dsc.y & 0xffffu);
        int cnt = (int)(dsc.y >> 16);
        int rr = min(col, cnt - 1);
        unsigned v = list[off + rr];
        int4 q = c4[v];
        int vz = q.y - pz, vy = q.z - py, vx = q.w - px;
        int abase = ((vz * 12 + vy) * 12 + vx) * 32 + dsel * 32 + halfsel * 16;
        const bf16x8* bq = (const bf16x8*)WcB + (size_t)cls * (NCHUNK * 64) + lane;

        f32x4 acc = {0.f, 0.f, 0.f, 0.f};
        #pragma unroll 1
        for (int dz = 0; dz < 5; ++dz) {
            #pragma unroll
            for (int dy = 0; dy < 5; ++dy) {
                int ab = abase + (dz * 144 + dy * 12) * 32;
                bf16x8 a0 = *(const bf16x8*)(halo + ab);
                bf16x8 a1 = *(const bf16x8*)(halo + ab + 64);
                bf16x8 a2 = *(const bf16x8*)(halo + ab + 128);
                int ci0 = (dz * 5 + dy) * 3;
                bf16x8 b0 = bq[ci0 * 64];
                bf16x8 b1 = bq[ci0 * 64 + 64];
                bf16x8 b2 = bq[ci0 * 64 + 128];
                acc = __builtin_amdgcn_mfma_f32_16x16x32_bf16(a0, b0, acc, 0, 0, 0);
                acc = __builtin_amdgcn_mfma_f32_16x16x32_bf16(a1, b1, acc, 0, 0, 0);
                acc = __builtin_amdgcn_mfma_f32_16x16x32_bf16(a2, b2, acc, 0, 0, 0);
            }
        }
        int rowq = (lane >> 4) * 4;
        #pragma unroll
        for (int reg = 0; reg < 4; ++reg) {
            int orow = rowq + reg;
            if (orow < cnt) {
                unsigned vo = list[off + orow];
                out[(size_t)vo * 16 + col] = acc[reg];
            }
        }
    }
}

extern "C" void kernel_launch(void* const* d_in, const int* in_sizes, int n_in,
                              void* d_out, int out_size, void* d_ws, size_t ws_size,
                              hipStream_t stream) {
    const float* features = (const float*)d_in[0];
    const int*   coors    = (const int*)d_in[1];
    const float* W1       = (const float*)d_in[2];
    const float* W2       = (const float*)d_in[3];
    float* out = (float*)d_out;

    const size_t dense_elems = (size_t)NB * PD * PH * PW * NCIN;
    const size_t dense_bytes = dense_elems * sizeof(__hip_bfloat16);     // 80.3 MB
    char* p = (char*)d_ws;
    __hip_bfloat16* dense = (__hip_bfloat16*)p;
    p += ((dense_bytes + 255) / 256) * 256;
    __hip_bfloat16* WcB = (__hip_bfloat16*)p;                            // 2.07MB
    p += (((size_t)27 * NCHUNK * 512 * 2 + 255) / 256) * 256;
    unsigned int* cnt = (unsigned int*)p;                                // 442KB
    p += (((size_t)NKEY * 4 + 255) / 256) * 256;
    unsigned int* cur = (unsigned int*)p;                                // 442KB
    p += (((size_t)NKEY * 4 + 255) / 256) * 256;
    unsigned int* ngroups = (unsigned int*)p; p += NTILES * 4;           // 16KB
    unsigned int* vcnt = (unsigned int*)p;    p += NTILES * 4;           // 16KB
    unsigned int* vbase = (unsigned int*)p;   p += NTILES * 4;           // 16KB
    uint2* gdesc = (uint2*)p;                                            // 2MB
    p += (size_t)NTILES * GCAP * 8;
    unsigned int* list = (unsigned int*)p;                               // 800KB
    float* P = (float*)list;        // wc scratch aliases list (746KB <= 800KB; used before bucket)

    hipMemsetAsync(dense, 0, dense_bytes, stream);
    hipMemsetAsync(cnt, 0, (size_t)NKEY * 4, stream);

    wc_p_kernel<<<729, 256, 0, stream>>>(W1, W2, P);
    wc_pack2_kernel<<<27 * NCHUNK, 512, 0, stream>>>(P, WcB);
    scatter_count_kernel<<<(NVOX * NCIN + 255) / 256, 256, 0, stream>>>(features, coors, dense, cnt);
    tile_cnt_kernel<<<NTILES / 256, 256, 0, stream>>>(cnt, vcnt);
    scan_kernel<<<1, 1024, 0, stream>>>(vcnt, vbase);
    emit_kernel<<<NTILES / 256, 256, 0, stream>>>(cnt, vbase, cur, gdesc, ngroups);
    bucket_kernel<<<(NVOX + 255) / 256, 256, 0, stream>>>(coors, cur, list);
    main_kernel<<<NTILES, 256, 0, stream>>>(coors, dense, WcB, gdesc, ngroups, list, out);
}